// Round 5
// baseline (170.301 us; speedup 1.0000x reference)
//
#include <hip/hip_runtime.h>
#include <hip/hip_fp16.h>

// score[e] = relu(h[src[e]]@W1s + h[dst[e]]@W1d + b1) @ W2 + b2
// N_NODES=100000, N_EDGES=1600000, H=64.
// Phase 1 (node_proj): GEMM [N x 64] @ [64 x 128] via bf16 MFMA 16x16x32,
//   epilogue quantizes to int8 rows P8[n] (h@W1s+b1) and Q8[n] (h@W1d),
//   64 B each, + per-node scale pair S[n]=(ps,qs).
// Phase 2 (r0-r3 evidence: dur insensitive to payload bytes, line pairing,
//   occupancy, ILP -> bound by random 128-B line-fill rate into the
//   per-XCD L2s, ~25G fills/s). Fix = locality:
//   2a (bucket_scatter): bin edges into 128 buckets (8 src-slices x 16
//      dst-slices) as packed u64 records, fixed-stride regions, LDS
//      histogram + bulk atomic slot grab.
//   2b (bucket_edge): XCD-contiguous swizzle pins src-slice x to XCD x ->
//      P-slice (0.8 MB) L2-resident for the whole kernel, Q-slice (0.4 MB)
//      resident per bucket. Compulsory fills ~58 MB vs ~150 MB random.
//      Scores scattered to out[eid].
// r4 fix: hipMemsetAsync removed (graph-capture suspect) -> counters
//   zeroed by a tiny kernel on-stream.
// Fallback (ws too small / ranges too big): r2-style direct edge kernel.

#define HF    64
#define PITCH 144    // int8 LDS row pitch in node_proj epilogue
#define TPB   2      // 64-node tiles per block (node_proj)
#define NBUCK 128    // 8 src-slices x 16 dst-slices
#define EPB   1024   // edges per block in bucket_edge

typedef __attribute__((ext_vector_type(8))) short bf16x8;
typedef __attribute__((ext_vector_type(4))) float f32x4;

__device__ __forceinline__ short f2bf(float x) {
    unsigned u = __builtin_bit_cast(unsigned, x);
    unsigned r = (u + 0x7fffu + ((u >> 16) & 1u)) >> 16;
    return (short)r;
}

__device__ __forceinline__ unsigned char q8(float v, float inv) {
    return (unsigned char)(int)rintf(fmaf(v, inv, 127.0f));
}

// ---------------- Phase 1: node projection via MFMA + int8 quant ----------
__global__ __launch_bounds__(256) void node_proj_kernel(
    const float* __restrict__ h, const float* __restrict__ W1,
    const float* __restrict__ b1, unsigned char* __restrict__ P8,
    unsigned char* __restrict__ Q8, float* __restrict__ S, int n_nodes)
{
    __shared__ unsigned char eb8[64 * PITCH];
    __shared__ float pscl[64];
    __shared__ float qscl[64];

    const int tid  = threadIdx.x;
    const int wave = tid >> 6;
    const int lane = tid & 63;
    const int q    = lane >> 4;
    const int n    = lane & 15;

    bf16x8 bfrag[8][2];
    #pragma unroll
    for (int t = 0; t < 8; ++t) {
        const float* wb = W1 + ((t >= 4) ? HF * HF : 0) + (t & 3) * 16 + n;
        #pragma unroll
        for (int kb = 0; kb < 2; ++kb) {
            #pragma unroll
            for (int j = 0; j < 8; ++j)
                bfrag[t][kb][j] = f2bf(wb[(kb * 32 + q * 8 + j) * HF]);
        }
    }
    const float bias_n  = b1[0 * 16 + n];
    const float bias_n1 = b1[1 * 16 + n];
    const float bias_n2 = b1[2 * 16 + n];
    const float bias_n3 = b1[3 * 16 + n];

    for (int it = 0; it < TPB; ++it) {
        const int tile = blockIdx.x * TPB + it;
        const int n0   = tile * 64;
        if (n0 >= n_nodes) break;
        const int nrow = (n_nodes - n0 < 64) ? (n_nodes - n0) : 64;

        bf16x8 a0, a1;
        {
            int row = n0 + wave * 16 + n;
            if (row >= n_nodes) row = n_nodes - 1;
            const float* hr = h + (size_t)row * HF + q * 8;
            const float4 u0 = *(const float4*)(hr);
            const float4 u1 = *(const float4*)(hr + 4);
            const float4 v0 = *(const float4*)(hr + 32);
            const float4 v1 = *(const float4*)(hr + 36);
            a0[0] = f2bf(u0.x); a0[1] = f2bf(u0.y); a0[2] = f2bf(u0.z); a0[3] = f2bf(u0.w);
            a0[4] = f2bf(u1.x); a0[5] = f2bf(u1.y); a0[6] = f2bf(u1.z); a0[7] = f2bf(u1.w);
            a1[0] = f2bf(v0.x); a1[1] = f2bf(v0.y); a1[2] = f2bf(v0.z); a1[3] = f2bf(v0.w);
            a1[4] = f2bf(v1.x); a1[5] = f2bf(v1.y); a1[6] = f2bf(v1.z); a1[7] = f2bf(v1.w);
        }

        f32x4 acc[8];
        #pragma unroll
        for (int t = 0; t < 8; ++t) {
            acc[t] = (f32x4){0.f, 0.f, 0.f, 0.f};
            acc[t] = __builtin_amdgcn_mfma_f32_16x16x32_bf16(a0, bfrag[t][0], acc[t], 0, 0, 0);
            acc[t] = __builtin_amdgcn_mfma_f32_16x16x32_bf16(a1, bfrag[t][1], acc[t], 0, 0, 0);
        }

        if (it > 0) __syncthreads();

        #pragma unroll
        for (int r = 0; r < 4; ++r) {
            const int row = wave * 16 + q * 4 + r;
            const float p0 = acc[0][r] + bias_n;
            const float p1 = acc[1][r] + bias_n1;
            const float p2 = acc[2][r] + bias_n2;
            const float p3 = acc[3][r] + bias_n3;
            const float q0 = acc[4][r], q1 = acc[5][r];
            const float q2 = acc[6][r], q3 = acc[7][r];

            float pa = fmaxf(fmaxf(__builtin_fabsf(p0), __builtin_fabsf(p1)),
                             fmaxf(__builtin_fabsf(p2), __builtin_fabsf(p3)));
            float qa = fmaxf(fmaxf(__builtin_fabsf(q0), __builtin_fabsf(q1)),
                             fmaxf(__builtin_fabsf(q2), __builtin_fabsf(q3)));
            #pragma unroll
            for (int m = 1; m < 16; m <<= 1) {
                pa = fmaxf(pa, __shfl_xor(pa, m, 16));
                qa = fmaxf(qa, __shfl_xor(qa, m, 16));
            }
            pa = fmaxf(pa, 1e-12f);
            qa = fmaxf(qa, 1e-12f);
            const float pinv = 127.0f / pa;
            const float qinv = 127.0f / qa;

            unsigned char* er = eb8 + row * PITCH;
            er[ 0 + n]      = q8(p0, pinv);
            er[16 + n]      = q8(p1, pinv);
            er[32 + n]      = q8(p2, pinv);
            er[48 + n]      = q8(p3, pinv);
            er[64 +  0 + n] = q8(q0, qinv);
            er[64 + 16 + n] = q8(q1, qinv);
            er[64 + 32 + n] = q8(q2, qinv);
            er[64 + 48 + n] = q8(q3, qinv);
            if (n == 0) {
                pscl[row] = pa * (1.0f / 127.0f);
                qscl[row] = qa * (1.0f / 127.0f);
            }
        }
        __syncthreads();

        // split stores: 64-B int8 rows -> P8 / Q8
        #pragma unroll
        for (int s = 0; s < 2; ++s) {
            const int idx  = tid + s * 256;
            const int row  = idx >> 3;
            const int part = idx & 7;         // 0..3 -> P8, 4..7 -> Q8
            if (row < nrow) {
                const uint4 v = *(const uint4*)&eb8[row * PITCH + part * 16];
                unsigned char* dstp = (part < 4)
                    ? (P8 + (size_t)(n0 + row) * HF + part * 16)
                    : (Q8 + (size_t)(n0 + row) * HF + (part - 4) * 16);
                *(uint4*)dstp = v;
            }
        }
        if (tid < nrow) {
            *(float2*)(S + 2 * (size_t)(n0 + tid)) =
                make_float2(pscl[tid], qscl[tid]);
        }
    }
}

// ---------------- counters zero (graph-capture-safe, no memset API) ------
__global__ void zero_counters_kernel(unsigned int* __restrict__ counters) {
    counters[threadIdx.x] = 0u;
}

// ---------------- Phase 2a: bucket scatter -------------------------------
// rec = eid | src<<21 | dst<<38  (eid<2^21, node<2^17 guarded on host)
#define SCAT_EPT 16
__global__ __launch_bounds__(256) void bucket_scatter_kernel(
    const int* __restrict__ src, const int* __restrict__ dst,
    unsigned long long* __restrict__ recs, unsigned int* __restrict__ counters,
    int n_edges, int cap, float invs, float invd)
{
    __shared__ unsigned int hist[NBUCK];
    __shared__ unsigned int gbase[NBUCK];
    __shared__ unsigned int rank[NBUCK];
    const int tid = threadIdx.x;
    if (tid < NBUCK) { hist[tid] = 0; rank[tid] = 0; }
    __syncthreads();

    const int blockbase = blockIdx.x * (256 * SCAT_EPT);
    int sv[SCAT_EPT], dv[SCAT_EPT], bk[SCAT_EPT];
    #pragma unroll
    for (int i = 0; i < SCAT_EPT; ++i) {
        const int e = blockbase + i * 256 + tid;
        int s_ = 0, d_ = 0, b = -1;
        if (e < n_edges) {
            s_ = src[e];
            d_ = dst[e];
            const int bs = min(7,  (int)((float)s_ * invs));
            const int bd = min(15, (int)((float)d_ * invd));
            b = bs * 16 + bd;
            atomicAdd(&hist[b], 1u);
        }
        sv[i] = s_; dv[i] = d_; bk[i] = b;
    }
    __syncthreads();
    if (tid < NBUCK) gbase[tid] = atomicAdd(&counters[tid], hist[tid]);
    __syncthreads();
    #pragma unroll
    for (int i = 0; i < SCAT_EPT; ++i) {
        const int b = bk[i];
        if (b >= 0) {
            const int e = blockbase + i * 256 + tid;
            const unsigned r = atomicAdd(&rank[b], 1u);
            const unsigned slot = gbase[b] + r;
            if (slot < (unsigned)cap) {
                recs[(size_t)b * cap + slot] =
                      (unsigned long long)(unsigned)e
                    | ((unsigned long long)(unsigned)sv[i] << 21)
                    | ((unsigned long long)(unsigned)dv[i] << 38);
            }
        }
    }
}

// ---------------- shared edge math ---------------------------------------
__device__ __forceinline__ float dot8q(uint2 pv, uint2 qv, float4 wa, float4 wb,
                                       float ps, float qs) {
    const float C = -127.0f * (ps + qs);
    float acc = 0.f;
    {
        const unsigned u = pv.x, v = qv.x;
        float x;
        x = fmaf((float)(u & 255u),         ps, fmaf((float)(v & 255u),         qs, C));
        acc = fmaf(fmaxf(x, 0.f), wa.x, acc);
        x = fmaf((float)((u >> 8) & 255u),  ps, fmaf((float)((v >> 8) & 255u),  qs, C));
        acc = fmaf(fmaxf(x, 0.f), wa.y, acc);
        x = fmaf((float)((u >> 16) & 255u), ps, fmaf((float)((v >> 16) & 255u), qs, C));
        acc = fmaf(fmaxf(x, 0.f), wa.z, acc);
        x = fmaf((float)(u >> 24),          ps, fmaf((float)(v >> 24),          qs, C));
        acc = fmaf(fmaxf(x, 0.f), wa.w, acc);
    }
    {
        const unsigned u = pv.y, v = qv.y;
        float x;
        x = fmaf((float)(u & 255u),         ps, fmaf((float)(v & 255u),         qs, C));
        acc = fmaf(fmaxf(x, 0.f), wb.x, acc);
        x = fmaf((float)((u >> 8) & 255u),  ps, fmaf((float)((v >> 8) & 255u),  qs, C));
        acc = fmaf(fmaxf(x, 0.f), wb.y, acc);
        x = fmaf((float)((u >> 16) & 255u), ps, fmaf((float)((v >> 16) & 255u), qs, C));
        acc = fmaf(fmaxf(x, 0.f), wb.z, acc);
        x = fmaf((float)(u >> 24),          ps, fmaf((float)(v >> 24),          qs, C));
        acc = fmaf(fmaxf(x, 0.f), wb.w, acc);
    }
    return acc;
}

__device__ __forceinline__ float red8(float v) {
    v += __shfl_xor(v, 4, 8);
    v += __shfl_xor(v, 2, 8);
    v += __shfl_xor(v, 1, 8);
    return v;
}

// ---------------- Phase 2b: bucketed edge kernel -------------------------
__global__ __launch_bounds__(256) void bucket_edge_kernel(
    const unsigned char* __restrict__ P8, const unsigned char* __restrict__ Q8,
    const float* __restrict__ S, const unsigned long long* __restrict__ recs,
    const unsigned int* __restrict__ counters,
    const float* __restrict__ W2, const float* __restrict__ b2,
    float* __restrict__ out, int cap, int bpb, int nblk)
{
    // XCD-contiguous swizzle: XCD x -> blocks [x*cpx, (x+1)*cpx) -> buckets
    // with src-slice x (bucket order is src-slice-major).
    const int bid = blockIdx.x;
    int swz = bid;
    if ((nblk & 7) == 0) {
        const int cpx = nblk >> 3;
        swz = (bid & 7) * cpx + (bid >> 3);
    }
    const int bucket = swz / bpb;
    const int chunk  = swz - bucket * bpb;
    const int cnt  = min((int)counters[bucket], cap);
    const int s0   = chunk * EPB;
    if (s0 >= cnt) return;
    const size_t base = (size_t)bucket * cap;

    const int tid = threadIdx.x;
    const int sub = tid & 7;
    const int g   = tid >> 3;
    const int j0  = sub * 8;
    const float4 w2a = *(const float4*)(W2 + j0);
    const float4 w2b = *(const float4*)(W2 + j0 + 4);
    const float bias2 = b2[0];

    #pragma unroll 1
    for (int it = 0; it < EPB / 256; ++it) {
        const int e8 = s0 + it * 256 + g * 8;    // group's first slot
        if (e8 >= cnt) break;                     // uniform within 8-lane group
        const int slot = e8 + sub;
        unsigned long long rec = 0;
        if (slot < cnt) rec = recs[base + slot];
        const int eid = (int)(rec & 0x1FFFFFu);
        const int sn  = (int)((rec >> 21) & 0x1FFFFu);
        const int dn  = (int)(rec >> 38);
        const float ps_own = S[2 * sn];
        const float qs_own = S[2 * dn + 1];

        uint2 p[8], q[8];
        #pragma unroll
        for (int j = 0; j < 8; ++j) {
            const int snj = __shfl(sn, j, 8);
            const int dnj = __shfl(dn, j, 8);
            p[j] = *(const uint2*)(P8 + (size_t)snj * HF + j0);
            q[j] = *(const uint2*)(Q8 + (size_t)dnj * HF + j0);
        }
        float sc[8];
        #pragma unroll
        for (int j = 0; j < 8; ++j) {
            sc[j] = red8(dot8q(p[j], q[j], w2a, w2b,
                               __shfl(ps_own, j, 8), __shfl(qs_own, j, 8)));
        }
        // lane j stores edge j's score (static selection, no scratch)
        float my = sc[0];
        #pragma unroll
        for (int j = 1; j < 8; ++j) my = (sub == j) ? sc[j] : my;
        if (slot < cnt) out[eid] = my + bias2;
    }
}

// ---------------- fallback: direct edge kernel (r2 structure) ------------
__global__ __launch_bounds__(256) void edge_score_kernel(
    const unsigned char* __restrict__ P8, const unsigned char* __restrict__ Q8,
    const float* __restrict__ S,
    const int* __restrict__ src, const int* __restrict__ dst,
    const float* __restrict__ W2, const float* __restrict__ b2,
    float* __restrict__ out, int n_edges)
{
    const int tid   = blockIdx.x * 256 + threadIdx.x;
    const int sub   = threadIdx.x & 7;
    const int group = tid >> 3;
    const int j0    = sub * 8;
    const int e0    = group * 8;
    if (e0 >= n_edges) return;

    const float4 w2a = *(const float4*)(W2 + j0);
    const float4 w2b = *(const float4*)(W2 + j0 + 4);
    const float bias2 = b2[0];

    if (e0 + 8 <= n_edges) {
        const int4 sA = *(const int4*)(src + e0);
        const int4 sB = *(const int4*)(src + e0 + 4);
        const int4 dA = *(const int4*)(dst + e0);
        const int4 dB = *(const int4*)(dst + e0 + 4);
        const float ps_own = S[2 * src[e0 + sub]];
        const float qs_own = S[2 * dst[e0 + sub] + 1];

        const uint2 p0 = *(const uint2*)(P8 + (size_t)sA.x * HF + j0);
        const uint2 q0 = *(const uint2*)(Q8 + (size_t)dA.x * HF + j0);
        const uint2 p1 = *(const uint2*)(P8 + (size_t)sA.y * HF + j0);
        const uint2 q1 = *(const uint2*)(Q8 + (size_t)dA.y * HF + j0);
        const uint2 p2 = *(const uint2*)(P8 + (size_t)sA.z * HF + j0);
        const uint2 q2 = *(const uint2*)(Q8 + (size_t)dA.z * HF + j0);
        const uint2 p3 = *(const uint2*)(P8 + (size_t)sA.w * HF + j0);
        const uint2 q3 = *(const uint2*)(Q8 + (size_t)dA.w * HF + j0);
        const uint2 p4 = *(const uint2*)(P8 + (size_t)sB.x * HF + j0);
        const uint2 q4 = *(const uint2*)(Q8 + (size_t)dB.x * HF + j0);
        const uint2 p5 = *(const uint2*)(P8 + (size_t)sB.y * HF + j0);
        const uint2 q5 = *(const uint2*)(Q8 + (size_t)dB.y * HF + j0);
        const uint2 p6 = *(const uint2*)(P8 + (size_t)sB.z * HF + j0);
        const uint2 q6 = *(const uint2*)(Q8 + (size_t)dB.z * HF + j0);
        const uint2 p7 = *(const uint2*)(P8 + (size_t)sB.w * HF + j0);
        const uint2 q7 = *(const uint2*)(Q8 + (size_t)dB.w * HF + j0);

        float s0 = red8(dot8q(p0, q0, w2a, w2b, __shfl(ps_own, 0, 8), __shfl(qs_own, 0, 8)));
        float s1 = red8(dot8q(p1, q1, w2a, w2b, __shfl(ps_own, 1, 8), __shfl(qs_own, 1, 8)));
        float s2 = red8(dot8q(p2, q2, w2a, w2b, __shfl(ps_own, 2, 8), __shfl(qs_own, 2, 8)));
        float s3 = red8(dot8q(p3, q3, w2a, w2b, __shfl(ps_own, 3, 8), __shfl(qs_own, 3, 8)));
        float s4 = red8(dot8q(p4, q4, w2a, w2b, __shfl(ps_own, 4, 8), __shfl(qs_own, 4, 8)));
        float s5 = red8(dot8q(p5, q5, w2a, w2b, __shfl(ps_own, 5, 8), __shfl(qs_own, 5, 8)));
        float s6 = red8(dot8q(p6, q6, w2a, w2b, __shfl(ps_own, 6, 8), __shfl(qs_own, 6, 8)));
        float s7 = red8(dot8q(p7, q7, w2a, w2b, __shfl(ps_own, 7, 8), __shfl(qs_own, 7, 8)));

        if (sub == 0) {
            *(float4*)(out + e0)     = make_float4(s0 + bias2, s1 + bias2,
                                                   s2 + bias2, s3 + bias2);
            *(float4*)(out + e0 + 4) = make_float4(s4 + bias2, s5 + bias2,
                                                   s6 + bias2, s7 + bias2);
        }
    } else {
        for (int e = e0; e < n_edges; ++e) {
            const int s = src[e];
            const int d = dst[e];
            const float ps = S[2 * s];
            const float qs = S[2 * d + 1];
            const uint2 pv = *(const uint2*)(P8 + (size_t)s * HF + j0);
            const uint2 qv = *(const uint2*)(Q8 + (size_t)d * HF + j0);
            float sc = red8(dot8q(pv, qv, w2a, w2b, ps, qs));
            if (sub == 0) out[e] = sc + bias2;
        }
    }
}

extern "C" void kernel_launch(void* const* d_in, const int* in_sizes, int n_in,
                              void* d_out, int out_size, void* d_ws, size_t ws_size,
                              hipStream_t stream) {
    const float* h   = (const float*)d_in[0];
    const int*   src = (const int*)d_in[1];
    const int*   dst = (const int*)d_in[2];
    const float* W1  = (const float*)d_in[3];
    const float* b1  = (const float*)d_in[4];
    const float* W2  = (const float*)d_in[5];
    const float* b2  = (const float*)d_in[6];
    float* out = (float*)d_out;

    const int n_nodes = in_sizes[0] / HF;
    const int n_edges = in_sizes[1];

    unsigned char* P8 = (unsigned char*)d_ws;                        // n*64
    unsigned char* Q8 = P8 + (size_t)n_nodes * HF;                   // n*64
    float* S = (float*)(Q8 + (size_t)n_nodes * HF);                  // n*2 f32
    unsigned int* counters = (unsigned int*)(S + 2 * (size_t)n_nodes);
    unsigned long long* recs = (unsigned long long*)
        (((uintptr_t)(counters + NBUCK) + 7) & ~(uintptr_t)7);

    // bucket capacity: mean + 12.5% + 256 slack, rounded up to EPB
    int cap = (n_edges / NBUCK + n_edges / (NBUCK * 8) + 256 + EPB - 1) / EPB * EPB;
    if (cap < EPB) cap = EPB;
    const size_t need = (size_t)((char*)(recs + (size_t)NBUCK * cap) - (char*)d_ws);
    const bool bucketed = (need <= ws_size) &&
                          (n_edges < (1 << 21)) && (n_nodes < (1 << 17));

    const int ntiles = (n_nodes + 63) / 64;
    const int nb1 = (ntiles + TPB - 1) / TPB;
    node_proj_kernel<<<nb1, 256, 0, stream>>>(h, W1, b1, P8, Q8, S, n_nodes);

    if (bucketed) {
        zero_counters_kernel<<<1, NBUCK, 0, stream>>>(counters);
        const int sblocks = (n_edges + 256 * SCAT_EPT - 1) / (256 * SCAT_EPT);
        bucket_scatter_kernel<<<sblocks, 256, 0, stream>>>(
            src, dst, recs, counters, n_edges, cap,
            8.0f / (float)n_nodes, 16.0f / (float)n_nodes);
        const int bpb  = cap / EPB;
        const int nblk = NBUCK * bpb;
        bucket_edge_kernel<<<nblk, 256, 0, stream>>>(
            P8, Q8, S, recs, counters, W2, b2, out, cap, bpb, nblk);
    } else {
        const int ngroups = (n_edges + 7) / 8;
        const int nb2 = (ngroups + 31) / 32;
        edge_score_kernel<<<nb2, 256, 0, stream>>>(
            P8, Q8, S, src, dst, W2, b2, out, n_edges);
    }
}

// Round 6
// 143.626 us; speedup vs baseline: 1.1857x; 1.1857x over previous
//
#include <hip/hip_runtime.h>
#include <hip/hip_fp16.h>

// score[e] = relu(h[src[e]]@W1s + h[dst[e]]@W1d + b1) @ W2 + b2
// N_NODES=100000, N_EDGES=1600000, H=64.
//
// Phase 1 (node_proj): GEMM [N x 64] @ [64 x 128] via bf16 MFMA 16x16x32.
//   Epilogue quantizes P (=h@W1s+b1) and Q (=h@W1d) rows to int8 with a
//   per-row scale snapped to a 32-step geometric grid amax_eff=0.25*2^(i/8);
//   the 5-bit index i is EMBEDDED in the LSBs of bytes 0..4 of the row
//   (costs <=1 LSB of noise on 5/64 elements). No separate scale array.
//
// Phase 2 (edge_score): r0-r5 established the edge phase is bound by the
//   random L2 REQUEST rate, not bytes (dur invariant at ~52us across
//   payload width, line pairing, occupancy, ILP, and halved HBM fetch;
//   all variants issued ~32 requests per 8 edges). This version cuts
//   requests ~2x: 16 payload gathers per 8 edges, ZERO scale gathers --
//   scales decoded from the payload's stolen LSBs (lane 0 of each 8-lane
//   group holds bytes 0..7 of the row) and broadcast via the shfl that
//   already existed.
//
// r5 lesson: bucketing cut HBM fetch 164->89 MB but not time (request-
//   bound, requests unchanged) and its scatter pass cost ~23us -> reverted.

#define HF    64
#define PITCH 144    // int8 LDS row pitch in node_proj epilogue
#define TPB   2      // 64-node tiles per block (node_proj)

typedef __attribute__((ext_vector_type(8))) short bf16x8;
typedef __attribute__((ext_vector_type(4))) float f32x4;

__device__ __forceinline__ short f2bf(float x) {
    unsigned u = __builtin_bit_cast(unsigned, x);
    unsigned r = (u + 0x7fffu + ((u >> 16) & 1u)) >> 16;
    return (short)r;
}

__device__ __forceinline__ unsigned char q8(float v, float inv) {
    // v in [-amax_eff, amax_eff], inv = 127/amax_eff -> result in [0, 254]
    return (unsigned char)(int)rintf(fmaf(v, inv, 127.0f));
}

// scale-grid: amax_eff = 0.25 * 2^(i/8), i in [0,31] (covers 0.25..3.67)
__device__ __forceinline__ int scale_idx(float amax) {
    const float lg = __log2f(amax * 4.0f) * 8.0f;
    int i = (int)ceilf(lg);
    return (i < 0) ? 0 : (i > 31 ? 31 : i);
}
__device__ __forceinline__ float scale_from_idx(int i) {
    return 0.25f * exp2f((float)i * 0.125f);
}

// ---------------- Phase 1: node projection via MFMA + int8 quant ----------
__global__ __launch_bounds__(256) void node_proj_kernel(
    const float* __restrict__ h, const float* __restrict__ W1,
    const float* __restrict__ b1, unsigned char* __restrict__ P8,
    unsigned char* __restrict__ Q8, int n_nodes)
{
    __shared__ unsigned char eb8[64 * PITCH];

    const int tid  = threadIdx.x;
    const int wave = tid >> 6;
    const int lane = tid & 63;
    const int q    = lane >> 4;
    const int n    = lane & 15;

    bf16x8 bfrag[8][2];
    #pragma unroll
    for (int t = 0; t < 8; ++t) {
        const float* wb = W1 + ((t >= 4) ? HF * HF : 0) + (t & 3) * 16 + n;
        #pragma unroll
        for (int kb = 0; kb < 2; ++kb) {
            #pragma unroll
            for (int j = 0; j < 8; ++j)
                bfrag[t][kb][j] = f2bf(wb[(kb * 32 + q * 8 + j) * HF]);
        }
    }
    const float bias_n  = b1[0 * 16 + n];
    const float bias_n1 = b1[1 * 16 + n];
    const float bias_n2 = b1[2 * 16 + n];
    const float bias_n3 = b1[3 * 16 + n];

    for (int it = 0; it < TPB; ++it) {
        const int tile = blockIdx.x * TPB + it;
        const int n0   = tile * 64;
        if (n0 >= n_nodes) break;
        const int nrow = (n_nodes - n0 < 64) ? (n_nodes - n0) : 64;

        bf16x8 a0, a1;
        {
            int row = n0 + wave * 16 + n;
            if (row >= n_nodes) row = n_nodes - 1;
            const float* hr = h + (size_t)row * HF + q * 8;
            const float4 u0 = *(const float4*)(hr);
            const float4 u1 = *(const float4*)(hr + 4);
            const float4 v0 = *(const float4*)(hr + 32);
            const float4 v1 = *(const float4*)(hr + 36);
            a0[0] = f2bf(u0.x); a0[1] = f2bf(u0.y); a0[2] = f2bf(u0.z); a0[3] = f2bf(u0.w);
            a0[4] = f2bf(u1.x); a0[5] = f2bf(u1.y); a0[6] = f2bf(u1.z); a0[7] = f2bf(u1.w);
            a1[0] = f2bf(v0.x); a1[1] = f2bf(v0.y); a1[2] = f2bf(v0.z); a1[3] = f2bf(v0.w);
            a1[4] = f2bf(v1.x); a1[5] = f2bf(v1.y); a1[6] = f2bf(v1.z); a1[7] = f2bf(v1.w);
        }

        f32x4 acc[8];
        #pragma unroll
        for (int t = 0; t < 8; ++t) {
            acc[t] = (f32x4){0.f, 0.f, 0.f, 0.f};
            acc[t] = __builtin_amdgcn_mfma_f32_16x16x32_bf16(a0, bfrag[t][0], acc[t], 0, 0, 0);
            acc[t] = __builtin_amdgcn_mfma_f32_16x16x32_bf16(a1, bfrag[t][1], acc[t], 0, 0, 0);
        }

        if (it > 0) __syncthreads();

        // ---- epilogue: row amax -> grid scale -> int8 + LSB-embedded idx --
        // C/D layout: col = n, row = q*4 + r (+wave*16). Row's 64 cols live
        // on the 16 lanes sharing q, 4 regs (t) each.
        #pragma unroll
        for (int r = 0; r < 4; ++r) {
            const int row = wave * 16 + q * 4 + r;
            const float p0 = acc[0][r] + bias_n;
            const float p1 = acc[1][r] + bias_n1;
            const float p2 = acc[2][r] + bias_n2;
            const float p3 = acc[3][r] + bias_n3;
            const float q0 = acc[4][r], q1 = acc[5][r];
            const float q2 = acc[6][r], q3 = acc[7][r];

            float pa = fmaxf(fmaxf(__builtin_fabsf(p0), __builtin_fabsf(p1)),
                             fmaxf(__builtin_fabsf(p2), __builtin_fabsf(p3)));
            float qa = fmaxf(fmaxf(__builtin_fabsf(q0), __builtin_fabsf(q1)),
                             fmaxf(__builtin_fabsf(q2), __builtin_fabsf(q3)));
            #pragma unroll
            for (int m = 1; m < 16; m <<= 1) {
                pa = fmaxf(pa, __shfl_xor(pa, m, 16));
                qa = fmaxf(qa, __shfl_xor(qa, m, 16));
            }
            pa = fmaxf(pa, 1e-6f);
            qa = fmaxf(qa, 1e-6f);
            const int   ip   = scale_idx(pa);
            const int   iq   = scale_idx(qa);
            const float pinv = 127.0f / scale_from_idx(ip);
            const float qinv = 127.0f / scale_from_idx(iq);

            unsigned char bp0 = q8(p0, pinv);   // byte t*16+n of P half
            unsigned char bq0 = q8(q0, qinv);   // byte (t-4)*16+n of Q half
            if (n < 5) {                        // steal LSBs of bytes 0..4
                bp0 = (unsigned char)((bp0 & 0xFEu) | ((ip >> n) & 1));
                bq0 = (unsigned char)((bq0 & 0xFEu) | ((iq >> n) & 1));
            }

            unsigned char* er = eb8 + row * PITCH;
            er[ 0 + n]      = bp0;
            er[16 + n]      = q8(p1, pinv);
            er[32 + n]      = q8(p2, pinv);
            er[48 + n]      = q8(p3, pinv);
            er[64 +  0 + n] = bq0;
            er[64 + 16 + n] = q8(q1, qinv);
            er[64 + 32 + n] = q8(q2, qinv);
            er[64 + 48 + n] = q8(q3, qinv);
        }
        __syncthreads();

        // split stores: 64-B int8 rows -> P8 / Q8
        #pragma unroll
        for (int s = 0; s < 2; ++s) {
            const int idx  = tid + s * 256;
            const int row  = idx >> 3;
            const int part = idx & 7;         // 0..3 -> P8, 4..7 -> Q8
            if (row < nrow) {
                const uint4 v = *(const uint4*)&eb8[row * PITCH + part * 16];
                unsigned char* dstp = (part < 4)
                    ? (P8 + (size_t)(n0 + row) * HF + part * 16)
                    : (Q8 + (size_t)(n0 + row) * HF + (part - 4) * 16);
                *(uint4*)dstp = v;
            }
        }
    }
}

// ---------------- Phase 2: per-edge score, scale from stolen LSBs ---------
// Lane holding bytes 0..7 of a row (sub==0) decodes the 5-bit grid index
// from the LSBs of bytes 0..4: bits b0..b3 in v.x, b4 in v.y.
__device__ __forceinline__ float dec_scale(uint2 v) {
    const unsigned x = v.x, y = v.y;
    const int i = (int)((x & 1u) | ((x >> 7) & 2u) | ((x >> 14) & 4u)
                      | ((x >> 21) & 8u) | ((y << 4) & 16u));
    return 0.25f * exp2f((float)i * 0.125f) * (1.0f / 127.0f);
}

__device__ __forceinline__ float dot8q(uint2 pv, uint2 qv, float4 wa, float4 wb,
                                       float ps, float qs) {
    const float C = -127.0f * (ps + qs);
    float acc = 0.f;
    {
        const unsigned u = pv.x, v = qv.x;
        float x;
        x = fmaf((float)(u & 255u),         ps, fmaf((float)(v & 255u),         qs, C));
        acc = fmaf(fmaxf(x, 0.f), wa.x, acc);
        x = fmaf((float)((u >> 8) & 255u),  ps, fmaf((float)((v >> 8) & 255u),  qs, C));
        acc = fmaf(fmaxf(x, 0.f), wa.y, acc);
        x = fmaf((float)((u >> 16) & 255u), ps, fmaf((float)((v >> 16) & 255u), qs, C));
        acc = fmaf(fmaxf(x, 0.f), wa.z, acc);
        x = fmaf((float)(u >> 24),          ps, fmaf((float)(v >> 24),          qs, C));
        acc = fmaf(fmaxf(x, 0.f), wa.w, acc);
    }
    {
        const unsigned u = pv.y, v = qv.y;
        float x;
        x = fmaf((float)(u & 255u),         ps, fmaf((float)(v & 255u),         qs, C));
        acc = fmaf(fmaxf(x, 0.f), wb.x, acc);
        x = fmaf((float)((u >> 8) & 255u),  ps, fmaf((float)((v >> 8) & 255u),  qs, C));
        acc = fmaf(fmaxf(x, 0.f), wb.y, acc);
        x = fmaf((float)((u >> 16) & 255u), ps, fmaf((float)((v >> 16) & 255u), qs, C));
        acc = fmaf(fmaxf(x, 0.f), wb.z, acc);
        x = fmaf((float)(u >> 24),          ps, fmaf((float)(v >> 24),          qs, C));
        acc = fmaf(fmaxf(x, 0.f), wb.w, acc);
    }
    return acc;
}

__device__ __forceinline__ float red8(float v) {
    v += __shfl_xor(v, 4, 8);
    v += __shfl_xor(v, 2, 8);
    v += __shfl_xor(v, 1, 8);
    return v;
}

__global__ __launch_bounds__(256) void edge_score_kernel(
    const unsigned char* __restrict__ P8, const unsigned char* __restrict__ Q8,
    const int* __restrict__ src, const int* __restrict__ dst,
    const float* __restrict__ W2, const float* __restrict__ b2,
    float* __restrict__ out, int n_edges)
{
    const int tid   = blockIdx.x * 256 + threadIdx.x;
    const int sub   = threadIdx.x & 7;
    const int group = tid >> 3;
    const int j0    = sub * 8;
    const int e0    = group * 8;
    if (e0 >= n_edges) return;

    const float4 w2a = *(const float4*)(W2 + j0);
    const float4 w2b = *(const float4*)(W2 + j0 + 4);
    const float bias2 = b2[0];

    if (e0 + 8 <= n_edges) {
        const int4 sA = *(const int4*)(src + e0);
        const int4 sB = *(const int4*)(src + e0 + 4);
        const int4 dA = *(const int4*)(dst + e0);
        const int4 dB = *(const int4*)(dst + e0 + 4);

        const uint2 p0 = *(const uint2*)(P8 + (size_t)sA.x * HF + j0);
        const uint2 q0 = *(const uint2*)(Q8 + (size_t)dA.x * HF + j0);
        const uint2 p1 = *(const uint2*)(P8 + (size_t)sA.y * HF + j0);
        const uint2 q1 = *(const uint2*)(Q8 + (size_t)dA.y * HF + j0);
        const uint2 p2 = *(const uint2*)(P8 + (size_t)sA.z * HF + j0);
        const uint2 q2 = *(const uint2*)(Q8 + (size_t)dA.z * HF + j0);
        const uint2 p3 = *(const uint2*)(P8 + (size_t)sA.w * HF + j0);
        const uint2 q3 = *(const uint2*)(Q8 + (size_t)dA.w * HF + j0);
        const uint2 p4 = *(const uint2*)(P8 + (size_t)sB.x * HF + j0);
        const uint2 q4 = *(const uint2*)(Q8 + (size_t)dB.x * HF + j0);
        const uint2 p5 = *(const uint2*)(P8 + (size_t)sB.y * HF + j0);
        const uint2 q5 = *(const uint2*)(Q8 + (size_t)dB.y * HF + j0);
        const uint2 p6 = *(const uint2*)(P8 + (size_t)sB.z * HF + j0);
        const uint2 q6 = *(const uint2*)(Q8 + (size_t)dB.z * HF + j0);
        const uint2 p7 = *(const uint2*)(P8 + (size_t)sB.w * HF + j0);
        const uint2 q7 = *(const uint2*)(Q8 + (size_t)dB.w * HF + j0);

        // scales decoded from lane 0's bytes (LSBs of bytes 0..4 of the row)
        const float ps0 = __shfl(dec_scale(p0), 0, 8), qs0 = __shfl(dec_scale(q0), 0, 8);
        const float ps1 = __shfl(dec_scale(p1), 0, 8), qs1 = __shfl(dec_scale(q1), 0, 8);
        const float ps2 = __shfl(dec_scale(p2), 0, 8), qs2 = __shfl(dec_scale(q2), 0, 8);
        const float ps3 = __shfl(dec_scale(p3), 0, 8), qs3 = __shfl(dec_scale(q3), 0, 8);
        const float ps4 = __shfl(dec_scale(p4), 0, 8), qs4 = __shfl(dec_scale(q4), 0, 8);
        const float ps5 = __shfl(dec_scale(p5), 0, 8), qs5 = __shfl(dec_scale(q5), 0, 8);
        const float ps6 = __shfl(dec_scale(p6), 0, 8), qs6 = __shfl(dec_scale(q6), 0, 8);
        const float ps7 = __shfl(dec_scale(p7), 0, 8), qs7 = __shfl(dec_scale(q7), 0, 8);

        const float s0 = red8(dot8q(p0, q0, w2a, w2b, ps0, qs0));
        const float s1 = red8(dot8q(p1, q1, w2a, w2b, ps1, qs1));
        const float s2 = red8(dot8q(p2, q2, w2a, w2b, ps2, qs2));
        const float s3 = red8(dot8q(p3, q3, w2a, w2b, ps3, qs3));
        const float s4 = red8(dot8q(p4, q4, w2a, w2b, ps4, qs4));
        const float s5 = red8(dot8q(p5, q5, w2a, w2b, ps5, qs5));
        const float s6 = red8(dot8q(p6, q6, w2a, w2b, ps6, qs6));
        const float s7 = red8(dot8q(p7, q7, w2a, w2b, ps7, qs7));

        if (sub == 0) {
            *(float4*)(out + e0)     = make_float4(s0 + bias2, s1 + bias2,
                                                   s2 + bias2, s3 + bias2);
            *(float4*)(out + e0 + 4) = make_float4(s4 + bias2, s5 + bias2,
                                                   s6 + bias2, s7 + bias2);
        }
    } else {
        for (int e = e0; e < n_edges; ++e) {
            const int s = src[e];
            const int d = dst[e];
            const uint2 pv = *(const uint2*)(P8 + (size_t)s * HF + j0);
            const uint2 qv = *(const uint2*)(Q8 + (size_t)d * HF + j0);
            const float ps = __shfl(dec_scale(pv), 0, 8);
            const float qs = __shfl(dec_scale(qv), 0, 8);
            float sc = red8(dot8q(pv, qv, w2a, w2b, ps, qs));
            if (sub == 0) out[e] = sc + bias2;
        }
    }
}

extern "C" void kernel_launch(void* const* d_in, const int* in_sizes, int n_in,
                              void* d_out, int out_size, void* d_ws, size_t ws_size,
                              hipStream_t stream) {
    const float* h   = (const float*)d_in[0];
    const int*   src = (const int*)d_in[1];
    const int*   dst = (const int*)d_in[2];
    const float* W1  = (const float*)d_in[3];
    const float* b1  = (const float*)d_in[4];
    const float* W2  = (const float*)d_in[5];
    const float* b2  = (const float*)d_in[6];
    float* out = (float*)d_out;

    const int n_nodes = in_sizes[0] / HF;
    const int n_edges = in_sizes[1];

    unsigned char* P8 = (unsigned char*)d_ws;                 // n*64
    unsigned char* Q8 = P8 + (size_t)n_nodes * HF;            // n*64

    const int ntiles = (n_nodes + 63) / 64;
    const int nb1 = (ntiles + TPB - 1) / TPB;
    node_proj_kernel<<<nb1, 256, 0, stream>>>(h, W1, b1, P8, Q8, n_nodes);

    const int ngroups = (n_edges + 7) / 8;    // 8 edges per 8-lane group
    const int nb2 = (ngroups + 31) / 32;      // 32 groups per 256-thr block
    edge_score_kernel<<<nb2, 256, 0, stream>>>(P8, Q8, src, dst, W2, b2, out, n_edges);
}

// Round 7
// 142.381 us; speedup vs baseline: 1.1961x; 1.0087x over previous
//
#include <hip/hip_runtime.h>
#include <hip/hip_fp16.h>

// score[e] = relu(h[src[e]]@W1s + h[dst[e]]@W1d + b1) @ W2 + b2
// N_NODES=100000, N_EDGES=1600000, H=64.
//
// Phase 1 (node_proj): GEMM [N x 64] @ [64 x 128] via bf16 MFMA 16x16x32.
//   Epilogue quantizes P (=h@W1s+b1) and Q (=h@W1d) rows to int8 with a
//   per-row scale snapped to a 32-step geometric grid amax_eff=0.25*2^(i/8);
//   the 5-bit index i is EMBEDDED in the LSBs of bytes 0..4 of the row.
//   No separate scale array.
//
// Phase 2 (edge_score): r0-r6 model ladder: not byte-bound (r1), not
//   line-bound (r2), not latency/occupancy (r1) or ILP (r3), not
//   L2-locality (r5: fetch 164->89 MB, time flat), not segment-rate
//   (r6: half of all random segments removed -> only -10%). Surviving
//   model: vmem WAVE-INSTRUCTION issue cost (r6's -10% == its -11%
//   instruction reduction). This round: 4-lane x 16-B gather groups
//   (dwordx4) -> payload instructions halved (16 -> 8 per 64 edges) at
//   IDENTICAL bytes/segments/requests. Clean discriminator: if flat,
//   the edge phase is at its structural random-gather floor.

#define HF    64
#define PITCH 144    // int8 LDS row pitch in node_proj epilogue
#define TPB   2      // 64-node tiles per block (node_proj)

typedef __attribute__((ext_vector_type(8))) short bf16x8;
typedef __attribute__((ext_vector_type(4))) float f32x4;

__device__ __forceinline__ short f2bf(float x) {
    unsigned u = __builtin_bit_cast(unsigned, x);
    unsigned r = (u + 0x7fffu + ((u >> 16) & 1u)) >> 16;
    return (short)r;
}

__device__ __forceinline__ unsigned char q8(float v, float inv) {
    // v in [-amax_eff, amax_eff], inv = 127/amax_eff -> result in [0, 254]
    return (unsigned char)(int)rintf(fmaf(v, inv, 127.0f));
}

// scale-grid: amax_eff = 0.25 * 2^(i/8), i in [0,31] (covers 0.25..3.67)
__device__ __forceinline__ int scale_idx(float amax) {
    const float lg = __log2f(amax * 4.0f) * 8.0f;
    int i = (int)ceilf(lg);
    return (i < 0) ? 0 : (i > 31 ? 31 : i);
}
__device__ __forceinline__ float scale_from_idx(int i) {
    return 0.25f * exp2f((float)i * 0.125f);
}

// ---------------- Phase 1: node projection via MFMA + int8 quant ----------
__global__ __launch_bounds__(256) void node_proj_kernel(
    const float* __restrict__ h, const float* __restrict__ W1,
    const float* __restrict__ b1, unsigned char* __restrict__ P8,
    unsigned char* __restrict__ Q8, int n_nodes)
{
    __shared__ unsigned char eb8[64 * PITCH];

    const int tid  = threadIdx.x;
    const int wave = tid >> 6;
    const int lane = tid & 63;
    const int q    = lane >> 4;
    const int n    = lane & 15;

    bf16x8 bfrag[8][2];
    #pragma unroll
    for (int t = 0; t < 8; ++t) {
        const float* wb = W1 + ((t >= 4) ? HF * HF : 0) + (t & 3) * 16 + n;
        #pragma unroll
        for (int kb = 0; kb < 2; ++kb) {
            #pragma unroll
            for (int j = 0; j < 8; ++j)
                bfrag[t][kb][j] = f2bf(wb[(kb * 32 + q * 8 + j) * HF]);
        }
    }
    const float bias_n  = b1[0 * 16 + n];
    const float bias_n1 = b1[1 * 16 + n];
    const float bias_n2 = b1[2 * 16 + n];
    const float bias_n3 = b1[3 * 16 + n];

    for (int it = 0; it < TPB; ++it) {
        const int tile = blockIdx.x * TPB + it;
        const int n0   = tile * 64;
        if (n0 >= n_nodes) break;
        const int nrow = (n_nodes - n0 < 64) ? (n_nodes - n0) : 64;

        bf16x8 a0, a1;
        {
            int row = n0 + wave * 16 + n;
            if (row >= n_nodes) row = n_nodes - 1;
            const float* hr = h + (size_t)row * HF + q * 8;
            const float4 u0 = *(const float4*)(hr);
            const float4 u1 = *(const float4*)(hr + 4);
            const float4 v0 = *(const float4*)(hr + 32);
            const float4 v1 = *(const float4*)(hr + 36);
            a0[0] = f2bf(u0.x); a0[1] = f2bf(u0.y); a0[2] = f2bf(u0.z); a0[3] = f2bf(u0.w);
            a0[4] = f2bf(u1.x); a0[5] = f2bf(u1.y); a0[6] = f2bf(u1.z); a0[7] = f2bf(u1.w);
            a1[0] = f2bf(v0.x); a1[1] = f2bf(v0.y); a1[2] = f2bf(v0.z); a1[3] = f2bf(v0.w);
            a1[4] = f2bf(v1.x); a1[5] = f2bf(v1.y); a1[6] = f2bf(v1.z); a1[7] = f2bf(v1.w);
        }

        f32x4 acc[8];
        #pragma unroll
        for (int t = 0; t < 8; ++t) {
            acc[t] = (f32x4){0.f, 0.f, 0.f, 0.f};
            acc[t] = __builtin_amdgcn_mfma_f32_16x16x32_bf16(a0, bfrag[t][0], acc[t], 0, 0, 0);
            acc[t] = __builtin_amdgcn_mfma_f32_16x16x32_bf16(a1, bfrag[t][1], acc[t], 0, 0, 0);
        }

        if (it > 0) __syncthreads();

        // ---- epilogue: row amax -> grid scale -> int8 + LSB-embedded idx --
        #pragma unroll
        for (int r = 0; r < 4; ++r) {
            const int row = wave * 16 + q * 4 + r;
            const float p0 = acc[0][r] + bias_n;
            const float p1 = acc[1][r] + bias_n1;
            const float p2 = acc[2][r] + bias_n2;
            const float p3 = acc[3][r] + bias_n3;
            const float q0 = acc[4][r], q1 = acc[5][r];
            const float q2 = acc[6][r], q3 = acc[7][r];

            float pa = fmaxf(fmaxf(__builtin_fabsf(p0), __builtin_fabsf(p1)),
                             fmaxf(__builtin_fabsf(p2), __builtin_fabsf(p3)));
            float qa = fmaxf(fmaxf(__builtin_fabsf(q0), __builtin_fabsf(q1)),
                             fmaxf(__builtin_fabsf(q2), __builtin_fabsf(q3)));
            #pragma unroll
            for (int m = 1; m < 16; m <<= 1) {
                pa = fmaxf(pa, __shfl_xor(pa, m, 16));
                qa = fmaxf(qa, __shfl_xor(qa, m, 16));
            }
            pa = fmaxf(pa, 1e-6f);
            qa = fmaxf(qa, 1e-6f);
            const int   ip   = scale_idx(pa);
            const int   iq   = scale_idx(qa);
            const float pinv = 127.0f / scale_from_idx(ip);
            const float qinv = 127.0f / scale_from_idx(iq);

            unsigned char bp0 = q8(p0, pinv);   // byte t*16+n of P half
            unsigned char bq0 = q8(q0, qinv);
            if (n < 5) {                        // steal LSBs of bytes 0..4
                bp0 = (unsigned char)((bp0 & 0xFEu) | ((ip >> n) & 1));
                bq0 = (unsigned char)((bq0 & 0xFEu) | ((iq >> n) & 1));
            }

            unsigned char* er = eb8 + row * PITCH;
            er[ 0 + n]      = bp0;
            er[16 + n]      = q8(p1, pinv);
            er[32 + n]      = q8(p2, pinv);
            er[48 + n]      = q8(p3, pinv);
            er[64 +  0 + n] = bq0;
            er[64 + 16 + n] = q8(q1, qinv);
            er[64 + 32 + n] = q8(q2, qinv);
            er[64 + 48 + n] = q8(q3, qinv);
        }
        __syncthreads();

        // split stores: 64-B int8 rows -> P8 / Q8
        #pragma unroll
        for (int s = 0; s < 2; ++s) {
            const int idx  = tid + s * 256;
            const int row  = idx >> 3;
            const int part = idx & 7;         // 0..3 -> P8, 4..7 -> Q8
            if (row < nrow) {
                const uint4 v = *(const uint4*)&eb8[row * PITCH + part * 16];
                unsigned char* dstp = (part < 4)
                    ? (P8 + (size_t)(n0 + row) * HF + part * 16)
                    : (Q8 + (size_t)(n0 + row) * HF + (part - 4) * 16);
                *(uint4*)dstp = v;
            }
        }
    }
}

// ---------------- Phase 2: per-edge score, 4-lane x 16-B groups -----------
// Scale decode: 5-bit grid index in LSBs of bytes 0..4 (bits b0..b3 in
// word0, b4 in word1) -> lane 0 of each 4-lane group holds bytes 0..15.
__device__ __forceinline__ float dec_scale4(uint4 v) {
    const unsigned x = v.x, y = v.y;
    const int i = (int)((x & 1u) | ((x >> 7) & 2u) | ((x >> 14) & 4u)
                      | ((x >> 21) & 8u) | ((y << 4) & 16u));
    return 0.25f * exp2f((float)i * 0.125f) * (1.0f / 127.0f);
}

__device__ __forceinline__ float dotw(unsigned u, unsigned v, float4 w,
                                      float ps, float qs, float C, float acc) {
    float x;
    x = fmaf((float)(u & 255u),         ps, fmaf((float)(v & 255u),         qs, C));
    acc = fmaf(fmaxf(x, 0.f), w.x, acc);
    x = fmaf((float)((u >> 8) & 255u),  ps, fmaf((float)((v >> 8) & 255u),  qs, C));
    acc = fmaf(fmaxf(x, 0.f), w.y, acc);
    x = fmaf((float)((u >> 16) & 255u), ps, fmaf((float)((v >> 16) & 255u), qs, C));
    acc = fmaf(fmaxf(x, 0.f), w.z, acc);
    x = fmaf((float)(u >> 24),          ps, fmaf((float)(v >> 24),          qs, C));
    acc = fmaf(fmaxf(x, 0.f), w.w, acc);
    return acc;
}

__device__ __forceinline__ float dot16q(uint4 pv, uint4 qv,
                                        float4 wa, float4 wb, float4 wc, float4 wd,
                                        float ps, float qs) {
    const float C = -127.0f * (ps + qs);
    float acc = 0.f;
    acc = dotw(pv.x, qv.x, wa, ps, qs, C, acc);
    acc = dotw(pv.y, qv.y, wb, ps, qs, C, acc);
    acc = dotw(pv.z, qv.z, wc, ps, qs, C, acc);
    acc = dotw(pv.w, qv.w, wd, ps, qs, C, acc);
    return acc;
}

__device__ __forceinline__ float red4(float v) {
    v += __shfl_xor(v, 2, 4);
    v += __shfl_xor(v, 1, 4);
    return v;
}

__global__ __launch_bounds__(256) void edge_score_kernel(
    const unsigned char* __restrict__ P8, const unsigned char* __restrict__ Q8,
    const int* __restrict__ src, const int* __restrict__ dst,
    const float* __restrict__ W2, const float* __restrict__ b2,
    float* __restrict__ out, int n_edges)
{
    const int tid   = blockIdx.x * 256 + threadIdx.x;
    const int sub   = threadIdx.x & 3;        // 4-lane group
    const int group = tid >> 2;
    const int j0    = sub * 16;               // 16 features / lane
    const int e0    = group * 8;
    if (e0 >= n_edges) return;

    const float4 w2a = *(const float4*)(W2 + j0);
    const float4 w2b = *(const float4*)(W2 + j0 + 4);
    const float4 w2c = *(const float4*)(W2 + j0 + 8);
    const float4 w2d = *(const float4*)(W2 + j0 + 12);
    const float bias2 = b2[0];

    if (e0 + 8 <= n_edges) {
        const int4 sA = *(const int4*)(src + e0);
        const int4 sB = *(const int4*)(src + e0 + 4);
        const int4 dA = *(const int4*)(dst + e0);
        const int4 dB = *(const int4*)(dst + e0 + 4);

        const uint4 p0 = *(const uint4*)(P8 + (size_t)sA.x * HF + j0);
        const uint4 q0 = *(const uint4*)(Q8 + (size_t)dA.x * HF + j0);
        const uint4 p1 = *(const uint4*)(P8 + (size_t)sA.y * HF + j0);
        const uint4 q1 = *(const uint4*)(Q8 + (size_t)dA.y * HF + j0);
        const uint4 p2 = *(const uint4*)(P8 + (size_t)sA.z * HF + j0);
        const uint4 q2 = *(const uint4*)(Q8 + (size_t)dA.z * HF + j0);
        const uint4 p3 = *(const uint4*)(P8 + (size_t)sA.w * HF + j0);
        const uint4 q3 = *(const uint4*)(Q8 + (size_t)dA.w * HF + j0);
        const uint4 p4 = *(const uint4*)(P8 + (size_t)sB.x * HF + j0);
        const uint4 q4 = *(const uint4*)(Q8 + (size_t)dB.x * HF + j0);
        const uint4 p5 = *(const uint4*)(P8 + (size_t)sB.y * HF + j0);
        const uint4 q5 = *(const uint4*)(Q8 + (size_t)dB.y * HF + j0);
        const uint4 p6 = *(const uint4*)(P8 + (size_t)sB.z * HF + j0);
        const uint4 q6 = *(const uint4*)(Q8 + (size_t)dB.z * HF + j0);
        const uint4 p7 = *(const uint4*)(P8 + (size_t)sB.w * HF + j0);
        const uint4 q7 = *(const uint4*)(Q8 + (size_t)dB.w * HF + j0);

        // scales from lane 0 of the 4-lane group (bytes 0..7 of each row)
        const float ps0 = __shfl(dec_scale4(p0), 0, 4), qs0 = __shfl(dec_scale4(q0), 0, 4);
        const float ps1 = __shfl(dec_scale4(p1), 0, 4), qs1 = __shfl(dec_scale4(q1), 0, 4);
        const float ps2 = __shfl(dec_scale4(p2), 0, 4), qs2 = __shfl(dec_scale4(q2), 0, 4);
        const float ps3 = __shfl(dec_scale4(p3), 0, 4), qs3 = __shfl(dec_scale4(q3), 0, 4);
        const float ps4 = __shfl(dec_scale4(p4), 0, 4), qs4 = __shfl(dec_scale4(q4), 0, 4);
        const float ps5 = __shfl(dec_scale4(p5), 0, 4), qs5 = __shfl(dec_scale4(q5), 0, 4);
        const float ps6 = __shfl(dec_scale4(p6), 0, 4), qs6 = __shfl(dec_scale4(q6), 0, 4);
        const float ps7 = __shfl(dec_scale4(p7), 0, 4), qs7 = __shfl(dec_scale4(q7), 0, 4);

        const float s0 = red4(dot16q(p0, q0, w2a, w2b, w2c, w2d, ps0, qs0));
        const float s1 = red4(dot16q(p1, q1, w2a, w2b, w2c, w2d, ps1, qs1));
        const float s2 = red4(dot16q(p2, q2, w2a, w2b, w2c, w2d, ps2, qs2));
        const float s3 = red4(dot16q(p3, q3, w2a, w2b, w2c, w2d, ps3, qs3));
        const float s4 = red4(dot16q(p4, q4, w2a, w2b, w2c, w2d, ps4, qs4));
        const float s5 = red4(dot16q(p5, q5, w2a, w2b, w2c, w2d, ps5, qs5));
        const float s6 = red4(dot16q(p6, q6, w2a, w2b, w2c, w2d, ps6, qs6));
        const float s7 = red4(dot16q(p7, q7, w2a, w2b, w2c, w2d, ps7, qs7));

        if (sub == 0) {
            *(float4*)(out + e0)     = make_float4(s0 + bias2, s1 + bias2,
                                                   s2 + bias2, s3 + bias2);
            *(float4*)(out + e0 + 4) = make_float4(s4 + bias2, s5 + bias2,
                                                   s6 + bias2, s7 + bias2);
        }
    } else {
        for (int e = e0; e < n_edges; ++e) {
            const int s = src[e];
            const int d = dst[e];
            const uint4 pv = *(const uint4*)(P8 + (size_t)s * HF + j0);
            const uint4 qv = *(const uint4*)(Q8 + (size_t)d * HF + j0);
            const float ps = __shfl(dec_scale4(pv), 0, 4);
            const float qs = __shfl(dec_scale4(qv), 0, 4);
            float sc = red4(dot16q(pv, qv, w2a, w2b, w2c, w2d, ps, qs));
            if (sub == 0) out[e] = sc + bias2;
        }
    }
}

extern "C" void kernel_launch(void* const* d_in, const int* in_sizes, int n_in,
                              void* d_out, int out_size, void* d_ws, size_t ws_size,
                              hipStream_t stream) {
    const float* h   = (const float*)d_in[0];
    const int*   src = (const int*)d_in[1];
    const int*   dst = (const int*)d_in[2];
    const float* W1  = (const float*)d_in[3];
    const float* b1  = (const float*)d_in[4];
    const float* W2  = (const float*)d_in[5];
    const float* b2  = (const float*)d_in[6];
    float* out = (float*)d_out;

    const int n_nodes = in_sizes[0] / HF;
    const int n_edges = in_sizes[1];

    unsigned char* P8 = (unsigned char*)d_ws;                 // n*64
    unsigned char* Q8 = P8 + (size_t)n_nodes * HF;            // n*64

    const int ntiles = (n_nodes + 63) / 64;
    const int nb1 = (ntiles + TPB - 1) / TPB;
    node_proj_kernel<<<nb1, 256, 0, stream>>>(h, W1, b1, P8, Q8, n_nodes);

    const int ngroups = (n_edges + 7) / 8;    // 8 edges per 4-lane group
    const int nb2 = (ngroups + 63) / 64;      // 64 groups per 256-thr block
    edge_score_kernel<<<nb2, 256, 0, stream>>>(P8, Q8, src, dst, W2, b2, out, n_edges);
}